// Round 14
// baseline (70.521 us; speedup 1.0000x reference)
//
#include <hip/hip_runtime.h>
#include <stdint.h>
#include <stddef.h>

typedef __bf16 bf16;
typedef unsigned long long u64;
typedef __attribute__((ext_vector_type(8))) __bf16 bf16x8;
typedef __attribute__((ext_vector_type(4))) __bf16 bf16x4;
typedef __attribute__((ext_vector_type(4))) float  f32x4;

// ---------------- geometry ----------------
// B = 262144. node: (B,19,4) f32, edge: (B,36,4) f32.
// compact first-4 nonzero rows of each -> x[32]; L1 32->256 relu; L2 256->128 relu;
// L3 128->34; log_softmax. Output (B,34) f32.
//
// R14 change vs R1 (62.1us): input loads are FULLY LINEAR (lane l reads float4
// j*64+l of the 16-sample region -> contiguous 1KB per instruction, no split
// cache lines) and compaction uses __ballot bitmasks + per-lane window extract.
// Everything else (weight image, stage path, compute, softmax) is R1 verbatim.
#define W1OFF  0               // 16 frags
#define W2OFF  (16*1024)       // 64 frags
#define W3OFF  (80*1024)       // 12 frags (N padded 34->48)
#define BOFF   (92*1024)       // b1[256] f32, b2[128], b3[48] = 1728B
#define IMGSZ  (92*1024 + 1728)
#define NCHUNK (IMGSZ/16)      // 5996 16B chunks
#define PERW   3072            // per-wave: x dbuf 2*1024 + stage 1024
#define LDSSZ  (IMGSZ + 8*PERW)  // 120512 B -> 1 block/CU, 8 waves

// swizzle for [16 rows][64B] bf16 tiles: XOR 16B-chunk index with (row>>1)&3
#define SWZ(s) ((((s)>>1)&3)<<4)

__global__ void prep_kernel(const float* __restrict__ W1, const float* __restrict__ b1,
                            const float* __restrict__ W2, const float* __restrict__ b2,
                            const float* __restrict__ W3, const float* __restrict__ b3,
                            char* __restrict__ img)
{
  int tid = blockIdx.x * 256 + threadIdx.x;
  if (tid < 92 * 64) {                       // 5888 weight chunks
    int fid = tid >> 6, l = tid & 63;
    int m = l & 15, gg = l >> 4;
    const float* W; int stride, n, k0;
    if (fid < 16)      { W = W1; stride = 256; n = fid * 16 + m;            k0 = gg * 8; }
    else if (fid < 80) { int f = fid - 16; W = W2; stride = 128; n = (f >> 3) * 16 + m; k0 = (f & 7) * 32 + gg * 8; }
    else               { int f = fid - 80; W = W3; stride = 34;  n = (f >> 2) * 16 + m; k0 = (f & 3) * 32 + gg * 8; }
    bf16x8 v;
    #pragma unroll
    for (int j = 0; j < 8; ++j) {
      float x = (stride == 34 && n >= 34) ? 0.f : W[(size_t)(k0 + j) * stride + n];
      v[j] = (bf16)x;
    }
    *(bf16x8*)(img + (size_t)tid * 16) = v;
  } else if (tid < 92 * 64 + 432) {          // biases, flat f32
    int i = tid - 92 * 64;
    float v;
    if (i < 256)      v = b1[i];
    else if (i < 384) v = b2[i - 256];
    else              { int j = i - 384; v = (j < 34) ? b3[j] : 0.f; }
    ((float*)(img + BOFF))[i] = v;
  }
}

#define NZ4(v) ((v).x != 0.f || (v).y != 0.f || (v).z != 0.f || (v).w != 0.f)

// (512,2): the proven non-spilling shell (R1: 108 VGPR).
__global__ __launch_bounds__(512, 2) void mlp_kernel(
    const float* __restrict__ node, const float* __restrict__ edge,
    const char* __restrict__ img, float* __restrict__ out)
{
  __shared__ __align__(16) char sm[LDSSZ];
  const int tid  = threadIdx.x;
  const int lane = tid & 63;
  const int w    = tid >> 6;                 // 0..7
  const int blk  = blockIdx.x;

  // stage weight image to LDS (coalesced 16B copies), one barrier total
  for (int c = tid; c < NCHUNK; c += 512)
    *(f32x4*)(sm + (size_t)c * 16) = *(const f32x4*)(img + (size_t)c * 16);
  __syncthreads();

  char* const xb0 = sm + IMGSZ + w * PERW;   // x tile buf A (1KB)
  char* const xb1 = xb0 + 1024;              // x tile buf B
  char* const stg = xb0 + 2048;              // inter-layer stage (1KB)
  const float* const b1p = (const float*)(sm + BOFF);
  const float* const b2p = b1p + 256;
  const float* const b3p = b1p + 384;

  const int g   = lane >> 4;   // mfma 16-lane group
  const int m16 = lane & 15;   // sample col (compute) / weight row
  const int cl  = lane & 3;    // zero-init lane role
  const int sl  = lane >> 2;   // zero-init row role (0..15)

  const float4* const np = (const float4*)node;   // 19 float4 per sample
  const float4* const ep = (const float4*)edge;   // 36 float4 per sample
  const f32x4 zf = {0.f, 0.f, 0.f, 0.f};

  float4 nf[5], ef[9];

  // linear loads: lane l holds float4 index j*64+l of the tile's region.
  auto issue_loads = [&](int sbase) {
    const float4* bn = np + (size_t)sbase * 19;   // 304 float4
    const float4* be = ep + (size_t)sbase * 36;   // 576 float4 (= 9*64 exactly)
    #pragma unroll
    for (int j = 0; j < 5; ++j) {
      int idx = j * 64 + lane;
      if (j == 4) idx = idx < 304 ? idx : 303;    // clamp: duplicate row 303 (idempotent)
      nf[j] = bn[idx];
    }
    #pragma unroll
    for (int j = 0; j < 9; ++j)
      ef[j] = be[j * 64 + lane];
  };

  // ballot-based compact: wave-uniform nonzero masks, per-lane window extract.
  auto compact = [&](char* dst) {
    // zero-init all 16 rows x 64B (old cl/sl roles; lockstep before data writes)
    bf16x4 zb; zb[0] = (bf16)0.f; zb[1] = (bf16)0.f; zb[2] = (bf16)0.f; zb[3] = (bf16)0.f;
    *(bf16x4*)(dst + sl * 64 + ((8 * cl)      ^ SWZ(sl))) = zb;
    *(bf16x4*)(dst + sl * 64 + ((8 * cl + 32) ^ SWZ(sl))) = zb;

    // one row of one sample, held by this lane
    auto node_row = [&](int j, u64 bm1, u64 b, u64 bp1, const float4& v) {
      int idx = j * 64 + lane;
      if (j == 4) idx = idx < 304 ? idx : 303;
      int s = idx / 19, r = idx % 19;             // compile-time divisor -> mul-magic
      int pos = idx - r;                          // = s*19
      int word = pos >> 6, sh = pos & 63;
      bool wj = (word == j);
      u64 lo = wj ? b : bm1;
      u64 hi = wj ? bp1 : b;
      u64 m = lo >> sh;
      if (sh) m |= hi << (64 - sh);
      unsigned int m19 = (unsigned int)m & 0x7FFFFu;
      if ((m19 >> r) & 1u) {
        int slot = __popc(m19 & ((1u << r) - 1u));
        if (slot < 4) {
          bf16x4 pk; pk[0] = (bf16)v.x; pk[1] = (bf16)v.y; pk[2] = (bf16)v.z; pk[3] = (bf16)v.w;
          *(bf16x4*)(dst + s * 64 + ((8 * slot) ^ SWZ(s))) = pk;
        }
      }
    };
    auto edge_row = [&](int j, u64 bm1, u64 b, u64 bp1, const float4& v) {
      int idx = j * 64 + lane;
      int s = idx / 36, r = idx % 36;
      int pos = idx - r;
      int word = pos >> 6, sh = pos & 63;
      bool wj = (word == j);
      u64 lo = wj ? b : bm1;
      u64 hi = wj ? bp1 : b;
      u64 m = lo >> sh;
      if (sh) m |= hi << (64 - sh);
      m &= 0xFFFFFFFFFull;                        // 36 bits
      if ((m >> r) & 1ull) {
        int slot = __popcll(m & ((1ull << r) - 1ull));
        if (slot < 4) {
          bf16x4 pk; pk[0] = (bf16)v.x; pk[1] = (bf16)v.y; pk[2] = (bf16)v.z; pk[3] = (bf16)v.w;
          *(bf16x4*)(dst + s * 64 + ((32 + 8 * slot) ^ SWZ(s))) = pk;
        }
      }
    };

    // node: 5 ballots, then rows (limits live uniform masks)
    {
      u64 n0 = __ballot(NZ4(nf[0]));
      u64 n1 = __ballot(NZ4(nf[1]));
      u64 n2 = __ballot(NZ4(nf[2]));
      u64 n3 = __ballot(NZ4(nf[3]));
      u64 n4 = __ballot(NZ4(nf[4]));
      node_row(0, 0,  n0, n1, nf[0]);
      node_row(1, n0, n1, n2, nf[1]);
      node_row(2, n1, n2, n3, nf[2]);
      node_row(3, n2, n3, n4, nf[3]);
      node_row(4, n3, n4, 0,  nf[4]);
    }
    // edge: 9 ballots, then rows
    {
      u64 e0 = __ballot(NZ4(ef[0]));
      u64 e1 = __ballot(NZ4(ef[1]));
      u64 e2 = __ballot(NZ4(ef[2]));
      u64 e3 = __ballot(NZ4(ef[3]));
      u64 e4 = __ballot(NZ4(ef[4]));
      u64 e5 = __ballot(NZ4(ef[5]));
      u64 e6 = __ballot(NZ4(ef[6]));
      u64 e7 = __ballot(NZ4(ef[7]));
      u64 e8 = __ballot(NZ4(ef[8]));
      edge_row(0, 0,  e0, e1, ef[0]);
      edge_row(1, e0, e1, e2, ef[1]);
      edge_row(2, e1, e2, e3, ef[2]);
      edge_row(3, e2, e3, e4, ef[3]);
      edge_row(4, e3, e4, e5, ef[4]);
      edge_row(5, e4, e5, e6, ef[5]);
      edge_row(6, e5, e6, e7, ef[6]);
      edge_row(7, e6, e7, e8, ef[7]);
      edge_row(8, e7, e8, 0,  ef[8]);
    }
  };

  // prologue: pass 0 data
  issue_loads(blk * 1024 + w * 16);
  compact(xb0);

  #pragma unroll 1
  for (int p = 0; p < 8; ++p) {
    char* const xb = (p & 1) ? xb1 : xb0;
    char* const xn = (p & 1) ? xb0 : xb1;
    const int S = blk * 1024 + p * 128 + w * 16;
    const bool pf = (p < 7);

    if (pf) issue_loads(S + 128);            // prefetch next pass
    asm volatile("" ::: "memory");           // keep loads issued before compute

    // x B-fragment: lane holds x[s=m16][8g .. 8g+8)
    bf16x8 xf = *(const bf16x8*)(xb + m16 * 64 + ((16 * g) ^ SWZ(m16)));

    // ---- L1 (32->256) fused into L2 (256->128) per 32-feature chunk ----
    f32x4 acc2[8];
    #pragma unroll
    for (int i = 0; i < 8; ++i) acc2[i] = zf;

    #pragma unroll
    for (int kk = 0; kk < 8; ++kk) {
      #pragma unroll
      for (int t = 0; t < 2; ++t) {
        const int nt1 = kk * 2 + t;
        bf16x8 wf = *(const bf16x8*)(sm + W1OFF + nt1 * 1024 + lane * 16);
        f32x4 d = __builtin_amdgcn_mfma_f32_16x16x32_bf16(wf, xf, zf, 0, 0, 0);
        f32x4 b = *(const f32x4*)(b1p + nt1 * 16 + 4 * g);
        bf16x4 pk;
        #pragma unroll
        for (int r = 0; r < 4; ++r) pk[r] = (bf16)fmaxf(d[r] + b[r], 0.f);
        // D is [feature][sample]: lane has 4 consecutive features of sample m16
        *(bf16x4*)(stg + m16 * 64 + ((32 * t + 8 * g) ^ SWZ(m16))) = pk;
      }
      bf16x8 sf = *(const bf16x8*)(stg + m16 * 64 + ((16 * g) ^ SWZ(m16)));
      #pragma unroll
      for (int nt2 = 0; nt2 < 8; ++nt2) {
        bf16x8 wf = *(const bf16x8*)(sm + W2OFF + (nt2 * 8 + kk) * 1024 + lane * 16);
        acc2[nt2] = __builtin_amdgcn_mfma_f32_16x16x32_bf16(wf, sf, acc2[nt2], 0, 0, 0);
      }
    }

    // ---- L2 out -> L3 (128->48 padded) ----
    f32x4 acc3[3];
    #pragma unroll
    for (int i = 0; i < 3; ++i) acc3[i] = zf;

    #pragma unroll
    for (int k2 = 0; k2 < 4; ++k2) {
      #pragma unroll
      for (int t = 0; t < 2; ++t) {
        const int nt2 = k2 * 2 + t;
        f32x4 b = *(const f32x4*)(b2p + nt2 * 16 + 4 * g);
        bf16x4 pk;
        #pragma unroll
        for (int r = 0; r < 4; ++r) pk[r] = (bf16)fmaxf(acc2[nt2][r] + b[r], 0.f);
        *(bf16x4*)(stg + m16 * 64 + ((32 * t + 8 * g) ^ SWZ(m16))) = pk;
      }
      bf16x8 sf = *(const bf16x8*)(stg + m16 * 64 + ((16 * g) ^ SWZ(m16)));
      #pragma unroll
      for (int nt3 = 0; nt3 < 3; ++nt3) {
        bf16x8 wf = *(const bf16x8*)(sm + W3OFF + (nt3 * 4 + k2) * 1024 + lane * 16);
        acc3[nt3] = __builtin_amdgcn_mfma_f32_16x16x32_bf16(wf, sf, acc3[nt3], 0, 0, 0);
      }
    }

    // ---- log_softmax over 34 classes (features spread over 4 lane-groups) ----
    float z[12];
    #pragma unroll
    for (int nt3 = 0; nt3 < 3; ++nt3) {
      f32x4 b = *(const f32x4*)(b3p + nt3 * 16 + 4 * g);
      #pragma unroll
      for (int r = 0; r < 4; ++r) {
        const int f = nt3 * 16 + 4 * g + r;
        z[nt3 * 4 + r] = (f < 34) ? (acc3[nt3][r] + b[r]) : -1e30f;
      }
    }
    float mx = z[0];
    #pragma unroll
    for (int i = 1; i < 12; ++i) mx = fmaxf(mx, z[i]);
    mx = fmaxf(mx, __shfl_xor(mx, 16));
    mx = fmaxf(mx, __shfl_xor(mx, 32));
    float sum = 0.f;
    #pragma unroll
    for (int i = 0; i < 12; ++i) sum += __expf(z[i] - mx);
    sum += __shfl_xor(sum, 16);
    sum += __shfl_xor(sum, 32);
    const float lse = mx + __logf(sum);

    float* orow = out + (size_t)(S + m16) * 34;
    *(float2*)(orow +  0 + 4 * g) = make_float2(z[0] - lse, z[1] - lse);
    *(float2*)(orow +  2 + 4 * g) = make_float2(z[2] - lse, z[3] - lse);
    *(float2*)(orow + 16 + 4 * g) = make_float2(z[4] - lse, z[5] - lse);
    *(float2*)(orow + 18 + 4 * g) = make_float2(z[6] - lse, z[7] - lse);
    if (g == 0)
      *(float2*)(orow + 32) = make_float2(z[8] - lse, z[9] - lse);

    if (pf) compact(xn);                     // build next pass's x tile
  }
}

extern "C" void kernel_launch(void* const* d_in, const int* in_sizes, int n_in,
                              void* d_out, int out_size, void* d_ws, size_t ws_size,
                              hipStream_t stream)
{
  const float* node = (const float*)d_in[0];
  const float* edge = (const float*)d_in[1];
  const float* W1   = (const float*)d_in[2];
  const float* b1   = (const float*)d_in[3];
  const float* W2   = (const float*)d_in[4];
  const float* b2   = (const float*)d_in[5];
  const float* W3   = (const float*)d_in[6];
  const float* b3   = (const float*)d_in[7];
  char* img = (char*)d_ws;

  prep_kernel<<<25, 256, 0, stream>>>(W1, b1, W2, b2, W3, b3, img);
  mlp_kernel<<<256, 512, 0, stream>>>(node, edge, img, (float*)d_out);
}

// Round 16
// 65.173 us; speedup vs baseline: 1.0821x; 1.0821x over previous
//
#include <hip/hip_runtime.h>
#include <stdint.h>
#include <stddef.h>

typedef __bf16 bf16;
typedef __attribute__((ext_vector_type(8))) __bf16 bf16x8;
typedef __attribute__((ext_vector_type(4))) __bf16 bf16x4;
typedef __attribute__((ext_vector_type(4))) float  f32x4;
typedef __attribute__((ext_vector_type(2))) float  f32x2;   // clang-native: ok for nt-store

// ---------------- geometry ----------------
// B = 262144. node: (B,19,4) f32, edge: (B,36,4) f32.
// compact first-4 nonzero rows of each -> x[32]; L1 32->256 relu; L2 256->128 relu;
// L3 128->34; log_softmax. Output (B,34) f32.
//
// R16 = R9 (best clean structure, 61.5us) + NON-TEMPORAL output stores.
// Rationale: replay working set = 231MB input + 36MB output + 24MB weights
// = 267MB, just over the 256MiB L3 -> output evicts half the input every
// replay (FETCH=113MB). nt stores keep the output out of L3 so the input
// stays resident; input then streams from L3 instead of 50% HBM.
//
// Weight image (bf16 fragment-linear, built by prep_kernel in d_ws):
//   frag = 1024B: lane l holds 16B = W[k0..k0+8)[n], n = nt*16+(l&15), k0 = kk*32+8*(l>>4).
#define W1OFF  0               // 16 frags
#define W2OFF  (16*1024)       // 64 frags
#define W3OFF  (80*1024)       // 12 frags (N padded 34->48)
#define BOFF   (92*1024)       // b1[256] f32, b2[128], b3[48] = 1728B
#define IMGSZ  (92*1024 + 1728)
#define NCHUNK (IMGSZ/16)      // 5996 16B chunks
#define PERW   2048            // per-wave: x tile 1KB + stage 1KB
#define NWAVE  16
#define LDSSZ  (IMGSZ + NWAVE*PERW)   // 128704 B -> 1 block/CU, 16 waves (4/SIMD)

// swizzle for [16 rows][64B] bf16 tiles: XOR 16B-chunk index with (row>>1)&3
#define SWZ(s) ((((s)>>1)&3)<<4)

__global__ void prep_kernel(const float* __restrict__ W1, const float* __restrict__ b1,
                            const float* __restrict__ W2, const float* __restrict__ b2,
                            const float* __restrict__ W3, const float* __restrict__ b3,
                            char* __restrict__ img)
{
  int tid = blockIdx.x * 256 + threadIdx.x;
  if (tid < 92 * 64) {                       // 5888 weight chunks
    int fid = tid >> 6, l = tid & 63;
    int m = l & 15, gg = l >> 4;
    const float* W; int stride, n, k0;
    if (fid < 16)      { W = W1; stride = 256; n = fid * 16 + m;            k0 = gg * 8; }
    else if (fid < 80) { int f = fid - 16; W = W2; stride = 128; n = (f >> 3) * 16 + m; k0 = (f & 7) * 32 + gg * 8; }
    else               { int f = fid - 80; W = W3; stride = 34;  n = (f >> 2) * 16 + m; k0 = (f & 3) * 32 + gg * 8; }
    bf16x8 v;
    #pragma unroll
    for (int j = 0; j < 8; ++j) {
      float x = (stride == 34 && n >= 34) ? 0.f : W[(size_t)(k0 + j) * stride + n];
      v[j] = (bf16)x;
    }
    *(bf16x8*)(img + (size_t)tid * 16) = v;
  } else if (tid < 92 * 64 + 432) {          // biases, flat f32
    int i = tid - 92 * 64;
    float v;
    if (i < 256)      v = b1[i];
    else if (i < 384) v = b2[i - 256];
    else              { int j = i - 384; v = (j < 34) ? b3[j] : 0.f; }
    ((float*)(img + BOFF))[i] = v;
  }
}

// 1024-thread block: 64-VGPR clamp, and this structure fits it cleanly
// (R9: VGPR 64, WRITE 34.9MB = output only, no spill). 16 waves/CU.
__global__ __launch_bounds__(1024, 1) void mlp_kernel(
    const float* __restrict__ node, const float* __restrict__ edge,
    const char* __restrict__ img, float* __restrict__ out)
{
  __shared__ __align__(16) char sm[LDSSZ];
  const int tid  = threadIdx.x;
  const int lane = tid & 63;
  const int w    = tid >> 6;                 // 0..15
  const int blk  = blockIdx.x;

  // stage full weight image to LDS (coalesced 16B copies), one barrier total
  for (int c = tid; c < NCHUNK; c += 1024)
    *(f32x4*)(sm + (size_t)c * 16) = *(const f32x4*)(img + (size_t)c * 16);
  __syncthreads();

  char* const xw  = sm + IMGSZ + w * PERW;   // x tile (1KB, wave-private)
  char* const stg = xw + 1024;               // inter-layer stage (1KB)
  const float* const b1p = (const float*)(sm + BOFF);
  const float* const b2p = b1p + 256;
  const float* const b3p = b1p + 384;

  const int g   = lane >> 4;   // mfma 16-lane group
  const int m16 = lane & 15;   // sample col (compute) / weight row
  const int cl  = lane & 3;    // compaction lane within sample
  const int sl  = lane >> 2;   // compaction sample-in-tile (0..15)

  const float4* const np = (const float4*)node;   // 19 float4 per sample
  const float4* const ep = (const float4*)edge;   // 36 float4 per sample
  const f32x4 zf = {0.f, 0.f, 0.f, 0.f};

  #pragma unroll 1
  for (int p = 0; p < 4; ++p) {
    const int S = blk * 1024 + p * 256 + w * 16;

    // ---- load raw rows, compact into xw ----
    {
      const int s = S + sl;
      float4 nf[5], ef[9];
      #pragma unroll
      for (int i = 0; i < 5; ++i) {
        const int r = cl + 4 * i;
        nf[i] = (r < 19) ? np[(size_t)s * 19 + r] : make_float4(0.f, 0.f, 0.f, 0.f);
      }
      #pragma unroll
      for (int i = 0; i < 9; ++i)
        ef[i] = ep[(size_t)s * 36 + cl + 4 * i];

      uint32_t nm = 0; unsigned long long em = 0;
      #pragma unroll
      for (int i = 0; i < 5; ++i) {
        const int r = cl + 4 * i;
        if (r < 19 && (nf[i].x != 0.f || nf[i].y != 0.f || nf[i].z != 0.f || nf[i].w != 0.f))
          nm |= (1u << r);
      }
      #pragma unroll
      for (int i = 0; i < 9; ++i) {
        const int r = cl + 4 * i;
        if (ef[i].x != 0.f || ef[i].y != 0.f || ef[i].z != 0.f || ef[i].w != 0.f)
          em |= (1ull << r);
      }
      nm |= __shfl_xor(nm, 1); nm |= __shfl_xor(nm, 2);
      em |= __shfl_xor(em, 1); em |= __shfl_xor(em, 2);
      // zero-init my two 8B slots of the row (8 slots covered by 4 lanes);
      // wave-lockstep: zeros land before data writes below.
      bf16x4 zb; zb[0] = (bf16)0.f; zb[1] = (bf16)0.f; zb[2] = (bf16)0.f; zb[3] = (bf16)0.f;
      *(bf16x4*)(xw + sl * 64 + ((8 * cl)      ^ SWZ(sl))) = zb;
      *(bf16x4*)(xw + sl * 64 + ((8 * cl + 32) ^ SWZ(sl))) = zb;
      #pragma unroll
      for (int i = 0; i < 5; ++i) {
        const int r = cl + 4 * i;
        if (r < 19 && ((nm >> r) & 1u)) {
          const int slot = __popc(nm & ((1u << r) - 1u));
          if (slot < 4) {
            bf16x4 pk; pk[0] = (bf16)nf[i].x; pk[1] = (bf16)nf[i].y; pk[2] = (bf16)nf[i].z; pk[3] = (bf16)nf[i].w;
            *(bf16x4*)(xw + sl * 64 + ((8 * slot) ^ SWZ(sl))) = pk;
          }
        }
      }
      #pragma unroll
      for (int i = 0; i < 9; ++i) {
        const int r = cl + 4 * i;
        if ((em >> r) & 1ull) {
          const int slot = __popcll(em & ((1ull << r) - 1ull));
          if (slot < 4) {
            bf16x4 pk; pk[0] = (bf16)ef[i].x; pk[1] = (bf16)ef[i].y; pk[2] = (bf16)ef[i].z; pk[3] = (bf16)ef[i].w;
            *(bf16x4*)(xw + sl * 64 + ((32 + 8 * slot) ^ SWZ(sl))) = pk;
          }
        }
      }
    }

    // x B-fragment: lane holds x[s=m16][8g .. 8g+8)
    bf16x8 xf = *(const bf16x8*)(xw + m16 * 64 + ((16 * g) ^ SWZ(m16)));

    // ---- L1 (32->256) fused into L2 (256->128) per 32-feature chunk ----
    f32x4 acc2[8];
    #pragma unroll
    for (int i = 0; i < 8; ++i) acc2[i] = zf;

    #pragma unroll 1
    for (int kk = 0; kk < 8; ++kk) {
      __builtin_amdgcn_sched_barrier(0);     // keep live ranges tight per iter
      #pragma unroll
      for (int t = 0; t < 2; ++t) {
        const int nt1 = kk * 2 + t;
        bf16x8 wf = *(const bf16x8*)(sm + W1OFF + nt1 * 1024 + lane * 16);
        f32x4 d = __builtin_amdgcn_mfma_f32_16x16x32_bf16(wf, xf, zf, 0, 0, 0);
        f32x4 b = *(const f32x4*)(b1p + nt1 * 16 + 4 * g);
        bf16x4 pk;
        #pragma unroll
        for (int r = 0; r < 4; ++r) pk[r] = (bf16)fmaxf(d[r] + b[r], 0.f);
        // D is [feature][sample]: lane has 4 consecutive features of sample m16
        *(bf16x4*)(stg + m16 * 64 + ((32 * t + 8 * g) ^ SWZ(m16))) = pk;
      }
      bf16x8 sf = *(const bf16x8*)(stg + m16 * 64 + ((16 * g) ^ SWZ(m16)));
      #pragma unroll
      for (int nt2 = 0; nt2 < 8; ++nt2) {
        bf16x8 wf = *(const bf16x8*)(sm + W2OFF + (nt2 * 8 + kk) * 1024 + lane * 16);
        acc2[nt2] = __builtin_amdgcn_mfma_f32_16x16x32_bf16(wf, sf, acc2[nt2], 0, 0, 0);
      }
    }

    // ---- L2 out -> L3 (128->48 padded) ----
    f32x4 acc3[3];
    #pragma unroll
    for (int i = 0; i < 3; ++i) acc3[i] = zf;

    #pragma unroll
    for (int k2 = 0; k2 < 4; ++k2) {
      #pragma unroll
      for (int t = 0; t < 2; ++t) {
        const int nt2 = k2 * 2 + t;
        f32x4 b = *(const f32x4*)(b2p + nt2 * 16 + 4 * g);
        bf16x4 pk;
        #pragma unroll
        for (int r = 0; r < 4; ++r) pk[r] = (bf16)fmaxf(acc2[nt2][r] + b[r], 0.f);
        *(bf16x4*)(stg + m16 * 64 + ((32 * t + 8 * g) ^ SWZ(m16))) = pk;
      }
      bf16x8 sf = *(const bf16x8*)(stg + m16 * 64 + ((16 * g) ^ SWZ(m16)));
      #pragma unroll
      for (int nt3 = 0; nt3 < 3; ++nt3) {
        bf16x8 wf = *(const bf16x8*)(sm + W3OFF + (nt3 * 4 + k2) * 1024 + lane * 16);
        acc3[nt3] = __builtin_amdgcn_mfma_f32_16x16x32_bf16(wf, sf, acc3[nt3], 0, 0, 0);
      }
    }

    // ---- log_softmax over 34 classes (features spread over 4 lane-groups) ----
    float z[12];
    #pragma unroll
    for (int nt3 = 0; nt3 < 3; ++nt3) {
      f32x4 b = *(const f32x4*)(b3p + nt3 * 16 + 4 * g);
      #pragma unroll
      for (int r = 0; r < 4; ++r) {
        const int f = nt3 * 16 + 4 * g + r;
        z[nt3 * 4 + r] = (f < 34) ? (acc3[nt3][r] + b[r]) : -1e30f;
      }
    }
    float mx = z[0];
    #pragma unroll
    for (int i = 1; i < 12; ++i) mx = fmaxf(mx, z[i]);
    mx = fmaxf(mx, __shfl_xor(mx, 16));
    mx = fmaxf(mx, __shfl_xor(mx, 32));
    float sum = 0.f;
    #pragma unroll
    for (int i = 0; i < 12; ++i) sum += __expf(z[i] - mx);
    sum += __shfl_xor(sum, 16);
    sum += __shfl_xor(sum, 32);
    const float lse = mx + __logf(sum);

    // ---- NON-TEMPORAL output stores (clang-native f32x2): keep the 36MB
    // output stream out of L3 so the 231MB input stays L3-resident. ----
    float* orow = out + (size_t)(S + m16) * 34;
    f32x2 o0; o0[0] = z[0] - lse; o0[1] = z[1] - lse;
    f32x2 o1; o1[0] = z[2] - lse; o1[1] = z[3] - lse;
    f32x2 o2; o2[0] = z[4] - lse; o2[1] = z[5] - lse;
    f32x2 o3; o3[0] = z[6] - lse; o3[1] = z[7] - lse;
    __builtin_nontemporal_store(o0, (f32x2*)(orow +  0 + 4 * g));
    __builtin_nontemporal_store(o1, (f32x2*)(orow +  2 + 4 * g));
    __builtin_nontemporal_store(o2, (f32x2*)(orow + 16 + 4 * g));
    __builtin_nontemporal_store(o3, (f32x2*)(orow + 18 + 4 * g));
    if (g == 0) {
      f32x2 o4; o4[0] = z[8] - lse; o4[1] = z[9] - lse;
      __builtin_nontemporal_store(o4, (f32x2*)(orow + 32));
    }
  }
}

extern "C" void kernel_launch(void* const* d_in, const int* in_sizes, int n_in,
                              void* d_out, int out_size, void* d_ws, size_t ws_size,
                              hipStream_t stream)
{
  const float* node = (const float*)d_in[0];
  const float* edge = (const float*)d_in[1];
  const float* W1   = (const float*)d_in[2];
  const float* b1   = (const float*)d_in[3];
  const float* W2   = (const float*)d_in[4];
  const float* b2   = (const float*)d_in[5];
  const float* W3   = (const float*)d_in[6];
  const float* b3   = (const float*)d_in[7];
  char* img = (char*)d_ws;

  prep_kernel<<<25, 256, 0, stream>>>(W1, b1, W2, b2, W3, b3, img);
  mlp_kernel<<<256, 1024, 0, stream>>>(node, edge, img, (float*)d_out);
}

// Round 17
// 61.795 us; speedup vs baseline: 1.1412x; 1.0547x over previous
//
#include <hip/hip_runtime.h>
#include <stdint.h>
#include <stddef.h>

typedef __bf16 bf16;
typedef __attribute__((ext_vector_type(8))) __bf16 bf16x8;
typedef __attribute__((ext_vector_type(4))) __bf16 bf16x4;
typedef __attribute__((ext_vector_type(4))) float  f32x4;

// ---------------- geometry ----------------
// B = 262144. node: (B,19,4) f32, edge: (B,36,4) f32.
// compact first-4 nonzero rows of each -> x[32]; L1 32->256 relu; L2 256->128 relu;
// L3 128->34; log_softmax. Output (B,34) f32.
//
// FINAL = R9 verbatim (measured optimum of the session, 61.5us):
// - weights as bf16 fragment-linear image in LDS (92KB), read conflict-light
// - 1024-thread block (16 waves/CU), rolled kk loop fits the 64-VGPR clamp
//   with zero spill (WRITE == output bytes only)
// - per-wave private 1KB x-tile + 1KB inter-layer stage, XOR-swizzled
// - regular stores (nt stores measured WORSE: R16, +3.7us, WRITE +17MB)
// Session kill-list (all measured null/negative): more waves (R9 vs R1),
// 2x ILP (R6), stage elimination (R11), M=32 MFMA (R12), T=2 weight-reuse
// (R13), linear+ballot loads (R14), nt stores (R16). ~62us is the blended
// memory operating point of the 267MB demand traffic.
//
// Weight image (bf16, fragment-linear, built by prep_kernel in d_ws):
//   frag = 1024B: lane l holds 16B = W[k0..k0+8)[n], n = nt*16+(l&15), k0 = kk*32+8*(l>>4).
#define W1OFF  0               // 16 frags
#define W2OFF  (16*1024)       // 64 frags
#define W3OFF  (80*1024)       // 12 frags (N padded 34->48)
#define BOFF   (92*1024)       // b1[256] f32, b2[128], b3[48] = 1728B
#define IMGSZ  (92*1024 + 1728)
#define NCHUNK (IMGSZ/16)      // 5996 16B chunks
#define PERW   2048            // per-wave: x tile 1KB + stage 1KB
#define NWAVE  16
#define LDSSZ  (IMGSZ + NWAVE*PERW)   // 128704 B -> 1 block/CU, 16 waves (4/SIMD)

// swizzle for [16 rows][64B] bf16 tiles: XOR 16B-chunk index with (row>>1)&3
#define SWZ(s) ((((s)>>1)&3)<<4)

__global__ void prep_kernel(const float* __restrict__ W1, const float* __restrict__ b1,
                            const float* __restrict__ W2, const float* __restrict__ b2,
                            const float* __restrict__ W3, const float* __restrict__ b3,
                            char* __restrict__ img)
{
  int tid = blockIdx.x * 256 + threadIdx.x;
  if (tid < 92 * 64) {                       // 5888 weight chunks
    int fid = tid >> 6, l = tid & 63;
    int m = l & 15, gg = l >> 4;
    const float* W; int stride, n, k0;
    if (fid < 16)      { W = W1; stride = 256; n = fid * 16 + m;            k0 = gg * 8; }
    else if (fid < 80) { int f = fid - 16; W = W2; stride = 128; n = (f >> 3) * 16 + m; k0 = (f & 7) * 32 + gg * 8; }
    else               { int f = fid - 80; W = W3; stride = 34;  n = (f >> 2) * 16 + m; k0 = (f & 3) * 32 + gg * 8; }
    bf16x8 v;
    #pragma unroll
    for (int j = 0; j < 8; ++j) {
      float x = (stride == 34 && n >= 34) ? 0.f : W[(size_t)(k0 + j) * stride + n];
      v[j] = (bf16)x;
    }
    *(bf16x8*)(img + (size_t)tid * 16) = v;
  } else if (tid < 92 * 64 + 432) {          // biases, flat f32
    int i = tid - 92 * 64;
    float v;
    if (i < 256)      v = b1[i];
    else if (i < 384) v = b2[i - 256];
    else              { int j = i - 384; v = (j < 34) ? b3[j] : 0.f; }
    ((float*)(img + BOFF))[i] = v;
  }
}

// 1024-thread block: 64-VGPR clamp, and this structure fits it cleanly
// (R9: VGPR 64, WRITE 34.9MB = output only, no spill). 16 waves/CU.
__global__ __launch_bounds__(1024, 1) void mlp_kernel(
    const float* __restrict__ node, const float* __restrict__ edge,
    const char* __restrict__ img, float* __restrict__ out)
{
  __shared__ __align__(16) char sm[LDSSZ];
  const int tid  = threadIdx.x;
  const int lane = tid & 63;
  const int w    = tid >> 6;                 // 0..15
  const int blk  = blockIdx.x;

  // stage full weight image to LDS (coalesced 16B copies), one barrier total
  for (int c = tid; c < NCHUNK; c += 1024)
    *(f32x4*)(sm + (size_t)c * 16) = *(const f32x4*)(img + (size_t)c * 16);
  __syncthreads();

  char* const xw  = sm + IMGSZ + w * PERW;   // x tile (1KB, wave-private)
  char* const stg = xw + 1024;               // inter-layer stage (1KB)
  const float* const b1p = (const float*)(sm + BOFF);
  const float* const b2p = b1p + 256;
  const float* const b3p = b1p + 384;

  const int g   = lane >> 4;   // mfma 16-lane group
  const int m16 = lane & 15;   // sample col (compute) / weight row
  const int cl  = lane & 3;    // compaction lane within sample
  const int sl  = lane >> 2;   // compaction sample-in-tile (0..15)

  const float4* const np = (const float4*)node;   // 19 float4 per sample
  const float4* const ep = (const float4*)edge;   // 36 float4 per sample
  const f32x4 zf = {0.f, 0.f, 0.f, 0.f};

  #pragma unroll 1
  for (int p = 0; p < 4; ++p) {
    const int S = blk * 1024 + p * 256 + w * 16;

    // ---- load raw rows, compact into xw ----
    {
      const int s = S + sl;
      float4 nf[5], ef[9];
      #pragma unroll
      for (int i = 0; i < 5; ++i) {
        const int r = cl + 4 * i;
        nf[i] = (r < 19) ? np[(size_t)s * 19 + r] : make_float4(0.f, 0.f, 0.f, 0.f);
      }
      #pragma unroll
      for (int i = 0; i < 9; ++i)
        ef[i] = ep[(size_t)s * 36 + cl + 4 * i];

      uint32_t nm = 0; unsigned long long em = 0;
      #pragma unroll
      for (int i = 0; i < 5; ++i) {
        const int r = cl + 4 * i;
        if (r < 19 && (nf[i].x != 0.f || nf[i].y != 0.f || nf[i].z != 0.f || nf[i].w != 0.f))
          nm |= (1u << r);
      }
      #pragma unroll
      for (int i = 0; i < 9; ++i) {
        const int r = cl + 4 * i;
        if (ef[i].x != 0.f || ef[i].y != 0.f || ef[i].z != 0.f || ef[i].w != 0.f)
          em |= (1ull << r);
      }
      nm |= __shfl_xor(nm, 1); nm |= __shfl_xor(nm, 2);
      em |= __shfl_xor(em, 1); em |= __shfl_xor(em, 2);
      // zero-init my two 8B slots of the row (8 slots covered by 4 lanes);
      // wave-lockstep: zeros land before data writes below.
      bf16x4 zb; zb[0] = (bf16)0.f; zb[1] = (bf16)0.f; zb[2] = (bf16)0.f; zb[3] = (bf16)0.f;
      *(bf16x4*)(xw + sl * 64 + ((8 * cl)      ^ SWZ(sl))) = zb;
      *(bf16x4*)(xw + sl * 64 + ((8 * cl + 32) ^ SWZ(sl))) = zb;
      #pragma unroll
      for (int i = 0; i < 5; ++i) {
        const int r = cl + 4 * i;
        if (r < 19 && ((nm >> r) & 1u)) {
          const int slot = __popc(nm & ((1u << r) - 1u));
          if (slot < 4) {
            bf16x4 pk; pk[0] = (bf16)nf[i].x; pk[1] = (bf16)nf[i].y; pk[2] = (bf16)nf[i].z; pk[3] = (bf16)nf[i].w;
            *(bf16x4*)(xw + sl * 64 + ((8 * slot) ^ SWZ(sl))) = pk;
          }
        }
      }
      #pragma unroll
      for (int i = 0; i < 9; ++i) {
        const int r = cl + 4 * i;
        if ((em >> r) & 1ull) {
          const int slot = __popcll(em & ((1ull << r) - 1ull));
          if (slot < 4) {
            bf16x4 pk; pk[0] = (bf16)ef[i].x; pk[1] = (bf16)ef[i].y; pk[2] = (bf16)ef[i].z; pk[3] = (bf16)ef[i].w;
            *(bf16x4*)(xw + sl * 64 + ((32 + 8 * slot) ^ SWZ(sl))) = pk;
          }
        }
      }
    }

    // x B-fragment: lane holds x[s=m16][8g .. 8g+8)
    bf16x8 xf = *(const bf16x8*)(xw + m16 * 64 + ((16 * g) ^ SWZ(m16)));

    // ---- L1 (32->256) fused into L2 (256->128) per 32-feature chunk ----
    f32x4 acc2[8];
    #pragma unroll
    for (int i = 0; i < 8; ++i) acc2[i] = zf;

    #pragma unroll 1
    for (int kk = 0; kk < 8; ++kk) {
      __builtin_amdgcn_sched_barrier(0);     // keep live ranges tight per iter
      #pragma unroll
      for (int t = 0; t < 2; ++t) {
        const int nt1 = kk * 2 + t;
        bf16x8 wf = *(const bf16x8*)(sm + W1OFF + nt1 * 1024 + lane * 16);
        f32x4 d = __builtin_amdgcn_mfma_f32_16x16x32_bf16(wf, xf, zf, 0, 0, 0);
        f32x4 b = *(const f32x4*)(b1p + nt1 * 16 + 4 * g);
        bf16x4 pk;
        #pragma unroll
        for (int r = 0; r < 4; ++r) pk[r] = (bf16)fmaxf(d[r] + b[r], 0.f);
        // D is [feature][sample]: lane has 4 consecutive features of sample m16
        *(bf16x4*)(stg + m16 * 64 + ((32 * t + 8 * g) ^ SWZ(m16))) = pk;
      }
      bf16x8 sf = *(const bf16x8*)(stg + m16 * 64 + ((16 * g) ^ SWZ(m16)));
      #pragma unroll
      for (int nt2 = 0; nt2 < 8; ++nt2) {
        bf16x8 wf = *(const bf16x8*)(sm + W2OFF + (nt2 * 8 + kk) * 1024 + lane * 16);
        acc2[nt2] = __builtin_amdgcn_mfma_f32_16x16x32_bf16(wf, sf, acc2[nt2], 0, 0, 0);
      }
    }

    // ---- L2 out -> L3 (128->48 padded) ----
    f32x4 acc3[3];
    #pragma unroll
    for (int i = 0; i < 3; ++i) acc3[i] = zf;

    #pragma unroll
    for (int k2 = 0; k2 < 4; ++k2) {
      #pragma unroll
      for (int t = 0; t < 2; ++t) {
        const int nt2 = k2 * 2 + t;
        f32x4 b = *(const f32x4*)(b2p + nt2 * 16 + 4 * g);
        bf16x4 pk;
        #pragma unroll
        for (int r = 0; r < 4; ++r) pk[r] = (bf16)fmaxf(acc2[nt2][r] + b[r], 0.f);
        *(bf16x4*)(stg + m16 * 64 + ((32 * t + 8 * g) ^ SWZ(m16))) = pk;
      }
      bf16x8 sf = *(const bf16x8*)(stg + m16 * 64 + ((16 * g) ^ SWZ(m16)));
      #pragma unroll
      for (int nt3 = 0; nt3 < 3; ++nt3) {
        bf16x8 wf = *(const bf16x8*)(sm + W3OFF + (nt3 * 4 + k2) * 1024 + lane * 16);
        acc3[nt3] = __builtin_amdgcn_mfma_f32_16x16x32_bf16(wf, sf, acc3[nt3], 0, 0, 0);
      }
    }

    // ---- log_softmax over 34 classes (features spread over 4 lane-groups) ----
    float z[12];
    #pragma unroll
    for (int nt3 = 0; nt3 < 3; ++nt3) {
      f32x4 b = *(const f32x4*)(b3p + nt3 * 16 + 4 * g);
      #pragma unroll
      for (int r = 0; r < 4; ++r) {
        const int f = nt3 * 16 + 4 * g + r;
        z[nt3 * 4 + r] = (f < 34) ? (acc3[nt3][r] + b[r]) : -1e30f;
      }
    }
    float mx = z[0];
    #pragma unroll
    for (int i = 1; i < 12; ++i) mx = fmaxf(mx, z[i]);
    mx = fmaxf(mx, __shfl_xor(mx, 16));
    mx = fmaxf(mx, __shfl_xor(mx, 32));
    float sum = 0.f;
    #pragma unroll
    for (int i = 0; i < 12; ++i) sum += __expf(z[i] - mx);
    sum += __shfl_xor(sum, 16);
    sum += __shfl_xor(sum, 32);
    const float lse = mx + __logf(sum);

    float* orow = out + (size_t)(S + m16) * 34;
    *(float2*)(orow +  0 + 4 * g) = make_float2(z[0] - lse, z[1] - lse);
    *(float2*)(orow +  2 + 4 * g) = make_float2(z[2] - lse, z[3] - lse);
    *(float2*)(orow + 16 + 4 * g) = make_float2(z[4] - lse, z[5] - lse);
    *(float2*)(orow + 18 + 4 * g) = make_float2(z[6] - lse, z[7] - lse);
    if (g == 0)
      *(float2*)(orow + 32) = make_float2(z[8] - lse, z[9] - lse);
  }
}

extern "C" void kernel_launch(void* const* d_in, const int* in_sizes, int n_in,
                              void* d_out, int out_size, void* d_ws, size_t ws_size,
                              hipStream_t stream)
{
  const float* node = (const float*)d_in[0];
  const float* edge = (const float*)d_in[1];
  const float* W1   = (const float*)d_in[2];
  const float* b1   = (const float*)d_in[3];
  const float* W2   = (const float*)d_in[4];
  const float* b2   = (const float*)d_in[5];
  const float* W3   = (const float*)d_in[6];
  const float* b3   = (const float*)d_in[7];
  char* img = (char*)d_ws;

  prep_kernel<<<25, 256, 0, stream>>>(W1, b1, W2, b2, W3, b3, img);
  mlp_kernel<<<256, 1024, 0, stream>>>(node, edge, img, (float*)d_out);
}